// Round 4
// baseline (212.227 us; speedup 1.0000x reference)
//
#include <hip/hip_runtime.h>
#include <math.h>

// Problem constants
#define HH 56
#define WW 56
#define NB 32
#define CC 256
#define PIX 3136               // 56*56
#define M_TOT 100352           // 32*3136
#define PADH 58
#define PADW 58
#define ACTQ_BYTES ((size_t)NB*PADH*PADW*CC)   // 27,553,792
#define WQ_BYTES ((size_t)9*CC*CC)             // 589,824
#define SBUF_BYTES ((size_t)M_TOT*CC*2)        // 51,380,224
#define BM 128
#define BN 256

typedef unsigned int u32;
typedef unsigned long long u64;
typedef int v4i __attribute__((ext_vector_type(4)));

// global_load_lds, width 16 (global -> LDS DMA; dest = wave base + lane*16)
typedef const __attribute__((address_space(1))) unsigned int* as1_u32p;
typedef __attribute__((address_space(3))) unsigned int* as3_u32p;
#define GLOAD_LDS16(g, l) \
  __builtin_amdgcn_global_load_lds((as1_u32p)(g), (as3_u32p)(l), 16, 0, 0)

// ---------------------------------------------------------------------------
// Pack weights: per-co mean (double), unbiased std, sw = 2^round(log2 mean|bw|),
// sign bytes wq[tap][co][ci] in {-1,+1}. Zeroes stat accumulators.
// ---------------------------------------------------------------------------
__global__ __launch_bounds__(256) void pack_weights_i8(
    const float* __restrict__ wt, signed char* __restrict__ wq,
    float* __restrict__ swv,
    long long* __restrict__ sumS, long long* __restrict__ sumSS) {
  int co = blockIdx.x;
  int t  = threadIdx.x;          // = ci
  int lane = t & 63, wid = t >> 6;

  float wv[9];
  const float* wp = wt + ((size_t)co*CC + t)*9;
  double psum = 0.0;
#pragma unroll
  for (int k = 0; k < 9; ++k) { wv[k] = wp[k]; psum += (double)wv[k]; }

  __shared__ double redm[4];
#pragma unroll
  for (int off = 32; off > 0; off >>= 1) psum += __shfl_xor(psum, off);
  if (lane == 0) redm[wid] = psum;
  __syncthreads();
  double mean = (redm[0]+redm[1]+redm[2]+redm[3]) * (1.0/2304.0);

  double pabs = 0.0, psq = 0.0;
#pragma unroll
  for (int k = 0; k < 9; ++k) {
    double d = (double)wv[k] - mean;
    pabs += fabs(d);
    psq  += d*d;
  }
#pragma unroll
  for (int off = 32; off > 0; off >>= 1) {
    pabs += __shfl_xor(pabs, off);
    psq  += __shfl_xor(psq,  off);
  }
  __shared__ double reda[4], redq[4];
  if (lane == 0) { reda[wid] = pabs; redq[wid] = psq; }
  __syncthreads();
  if (t == 0) {
    double sa = reda[0]+reda[1]+reda[2]+reda[3];
    double sq = redq[0]+redq[1]+redq[2]+redq[3];
    double stdv = sqrt(sq / 2303.0);                 // torch unbiased std
    double mabs = (sa * (1.0/2304.0)) / stdv;        // mean|bw|
    swv[co] = (float)exp2(rint(log2(mabs)));         // round half-to-even
    sumS[co]  = 0;
    sumSS[co] = 0;
  }
  // sign bytes: wq[k][co][ci]
#pragma unroll
  for (int k = 0; k < 9; ++k)
    wq[((size_t)k*CC + co)*CC + t] =
        (((double)wv[k] - mean) > 0.0) ? (signed char)1 : (signed char)-1;
}

// ---------------------------------------------------------------------------
// Pack activations: sign(x) -> i8 channel-last padded [n][ph][pw][ci].
// Border cells written as zeros here (memset fused away).
// ---------------------------------------------------------------------------
__global__ __launch_bounds__(256) void pack_acts_i8(
    const float* __restrict__ x, signed char* __restrict__ actq) {
  int n = blockIdx.y, tile = blockIdx.x;               // 53 tiles of 64 padded-pl
  int lane = threadIdx.x & 63, cw = threadIdx.x >> 6;  // cw: 64-ci group
  int pp = tile*64 + lane;
  if (pp >= PADH*PADW) return;
  int ph = pp / PADW, pw = pp - ph*PADW;
  signed char* dst = actq + ((size_t)(n*PADH + ph)*PADW + pw)*CC + cw*64;
  if (ph == 0 || ph == PADH-1 || pw == 0 || pw == PADW-1) {
    uint4 z = make_uint4(0u, 0u, 0u, 0u);
#pragma unroll
    for (int q = 0; q < 4; ++q) ((uint4*)dst)[q] = z;
    return;
  }
  int h = ph - 1, w = pw - 1;
  const float* xp = x + ((size_t)(n*CC + cw*64))*PIX + h*WW + w;
  u32 wrd[16];
#pragma unroll
  for (int c16 = 0; c16 < 16; ++c16) {
    u32 v = 0;
#pragma unroll
    for (int b = 0; b < 4; ++b) {
      float f = xp[(size_t)(c16*4 + b)*PIX];
      v |= (f > 0.0f ? 0x01u : 0xFFu) << (8*b);   // +1 / -1 as i8
    }
    wrd[c16] = v;
  }
#pragma unroll
  for (int q = 0; q < 4; ++q)
    ((uint4*)dst)[q] = make_uint4(wrd[4*q], wrd[4*q+1], wrd[4*q+2], wrd[4*q+3]);
}

// ---------------------------------------------------------------------------
// Binary implicit-GEMM conv, mfma_i32_16x16x64_i8. Block 128x256, 4 waves,
// wave tile 64x128 (32 MFMA/stage).
// Round 4: A DIRECT FROM GLOBAL (LDS was the 86%-busy pipe at R3). For this
// MFMA shape lane l's A-frag = row l&15, bytes (l>>4)*16.. of a 64B k-chunk:
// in channel-last actq that is a per-lane contiguous global_load_dwordx4,
// and the 4 quads of a row tile a full 64B line -> perfectly coalesced,
// L1-hit for the mirror wave. A is register double-buffered 1 stage ahead.
// LDS now stages B only (3 x 16KB). Removes 50KB/CU-stage of LDS traffic:
// LDS ~1130cy < MFMA ~1306cy per stage -> MFMA becomes the binding pipe.
// vmcnt: per iter issue [A(s+1) x4][B-DMA(s+3) x4]; steady wait vmcnt(4)
// (leaves B(s+3) in flight, drains A(s+1) + older B). Tail 4/0/0.
// B keeps the verified XOR chunk-swizzle (0 conflicts) + 2-barrier STEPM.
// ---------------------------------------------------------------------------

// B-only stage SN (tap SN>>2, k-chunk SN&3) into buffer BUF (0/1/2)
#define STAGEMB(SN, BUF) do {                                             \
    int tn_ = (SN) >> 2, kn_ = (SN) & 3;                                  \
    int boff_ = tn_*65536 + kn_*64;                                       \
    char* nb_ = (char*)lds + (BUF)*16384;                                 \
    GLOAD_LDS16(pB0 + boff_, nb_ + ldst);                                 \
    GLOAD_LDS16(pB1 + boff_, nb_ + 4096 + ldst);                         \
    GLOAD_LDS16(pB2 + boff_, nb_ + 8192 + ldst);                          \
    GLOAD_LDS16(pB3 + boff_, nb_ + 12288 + ldst);                        \
  } while (0)

// issue the 4 per-lane A-frag global loads for stage SN into AF[0..3]
#define ASTAGE(SN, AF) do {                                               \
    int tn_ = (SN) >> 2, kn_ = (SN) & 3;                                  \
    int aoff_ = ((tn_/3 - 1)*PADW + (tn_%3 - 1))*CC + kn_*64;             \
    AF[0] = *(const v4i*)(pA0g + aoff_);                                  \
    AF[1] = *(const v4i*)(pA1g + aoff_);                                  \
    AF[2] = *(const v4i*)(pA2g + aoff_);                                  \
    AF[3] = *(const v4i*)(pA3g + aoff_);                                  \
  } while (0)

// one K-stage: wait (counted) -> barrier -> issue A(s+1) -> read B frags ->
// lgkm drain + barrier -> B-DMA(s+3) into freed buffer -> 32 MFMA (setprio).
#define STEP(S, BUF, AFC, AFN, WTXT, DOB, DOA) do {                       \
    asm volatile("s_waitcnt " WTXT ::: "memory");                         \
    __builtin_amdgcn_s_barrier();                                         \
    if (DOA) { ASTAGE((S) + 1, AFN); }                                    \
    __builtin_amdgcn_sched_barrier(0);                                    \
    const char* cb_ = (const char*)lds + (BUF)*16384;                     \
    v4i bf[8];                                                            \
    _Pragma("unroll")                                                     \
    for (int j = 0; j < 8; ++j)                                           \
      bf[j] = *(const v4i*)(cb_ + (bc0 + j*16 + lm)*64 + rdo);            \
    asm volatile("s_waitcnt lgkmcnt(0)" ::: "memory");                    \
    __builtin_amdgcn_s_barrier();                                         \
    if (DOB) { STAGEMB((S) + 3, BUF); }                                   \
    __builtin_amdgcn_s_setprio(1);                                        \
    _Pragma("unroll")                                                     \
    for (int i = 0; i < 4; ++i)                                           \
      _Pragma("unroll")                                                   \
      for (int j = 0; j < 8; ++j)                                         \
        acc[i][j] = __builtin_amdgcn_mfma_i32_16x16x64_i8(AFC[i], bf[j],  \
                                                          acc[i][j], 0, 0, 0); \
    __builtin_amdgcn_s_setprio(0);                                        \
  } while (0)

template <bool S16>
__global__ __launch_bounds__(256, 2) void bconv_mfma(
    const signed char* __restrict__ actq, const signed char* __restrict__ wq,
    short* __restrict__ s16out, float* __restrict__ f32out,
    u64* __restrict__ sumS, u64* __restrict__ sumSS) {
  __shared__ char lds[49152] __attribute__((aligned(16)));  // 3 x B 16K
  __shared__ int colS[256], colQ[256];

  int t = threadIdx.x;
  int lane = t & 63, wv = t >> 6;
  int lm = lane & 15, quad = lane >> 4;
  int ar0 = (wv & 1) * 64;         // wave A-row base in tile (2 row groups)
  int bc0 = (wv >> 1) * 128;       // wave B-col base in tile (2 col groups)
  int Mbase = blockIdx.x * BM;

  colS[t] = 0; colQ[t] = 0;

  // B staging: thread t -> cols r, r+64, r+128, r+192, 16B chunk c16.
  // LDS dest LINEAR; global source chunk XOR-swizzled cs = c16 ^ ((r>>1)&3).
  int r = t >> 2, c16 = t & 3;
  int cs = c16 ^ ((r >> 1) & 3);
  const signed char* pB0 = wq + (size_t)r*CC + cs*16;
  const signed char* pB1 = pB0 +  64*CC;
  const signed char* pB2 = pB0 + 128*CC;
  const signed char* pB3 = pB0 + 192*CC;
  int ldst = t*16;                 // LDS dest: [col][64B] contiguous in t

  // B read side: lane (lm,quad) wants global chunk=quad of col ..+lm ->
  // LDS slot quad ^ ((col>>1)&3); (col>>1)&3 == (lm>>1)&3 for 16-aligned bases
  int rdo = (quad ^ ((lm >> 1) & 3)) * 16;

  // A direct-load per-lane bases: row = Mbase + ar0 + i*16 + lm (pixel),
  // k-offset quad*16 within the tap's 64B chunk (chunk base added per stage).
  const signed char *pA0g, *pA1g, *pA2g, *pA3g;
  {
    int P0 = Mbase + ar0 + lm;
#define MKPA(PVAR, DST) {                                                  \
      int n_ = (PVAR) / PIX, pl_ = (PVAR) % PIX;                           \
      int h_ = pl_ / WW, w_ = pl_ - h_*WW;                                 \
      DST = actq + ((size_t)(n_*PADH + h_+1)*PADW + (w_+1))*CC + quad*16; }
    MKPA(P0,      pA0g);
    MKPA(P0 + 16, pA1g);
    MKPA(P0 + 32, pA2g);
    MKPA(P0 + 48, pA3g);
#undef MKPA
  }

  v4i acc[4][8];
#pragma unroll
  for (int i = 0; i < 4; ++i)
#pragma unroll
    for (int j = 0; j < 8; ++j) acc[i][j] = 0;

  v4i af0[4], af1[4];              // A fragment double buffer (stage parity)

  // prologue: B 3-deep (12 DMA loads), then A(0) (4 loads)
  STAGEMB(0, 0);
  STAGEMB(1, 1);
  STAGEMB(2, 2);
  ASTAGE(0, af0);

  // stage s: tap = s>>2 (0..8), kq = s&3; 36 stages. Buffer period 3 x A
  // parity 2 => period 6. Stage 0 drains everything (prologue order B,B,B,A
  // puts A newest); steady vmcnt(4) leaves only B(s+3) in flight.
  STEP(0, 0, af0, af1, "vmcnt(0)", 1, 1);
  STEP(1, 1, af1, af0, "vmcnt(4)", 1, 1);
  STEP(2, 2, af0, af1, "vmcnt(4)", 1, 1);
  STEP(3, 0, af1, af0, "vmcnt(4)", 1, 1);
  STEP(4, 1, af0, af1, "vmcnt(4)", 1, 1);
  STEP(5, 2, af1, af0, "vmcnt(4)", 1, 1);
#pragma unroll 1
  for (int s = 6; s < 30; s += 6) {
    STEP(s + 0, 0, af0, af1, "vmcnt(4)", 1, 1);
    STEP(s + 1, 1, af1, af0, "vmcnt(4)", 1, 1);
    STEP(s + 2, 2, af0, af1, "vmcnt(4)", 1, 1);
    STEP(s + 3, 0, af1, af0, "vmcnt(4)", 1, 1);
    STEP(s + 4, 1, af0, af1, "vmcnt(4)", 1, 1);
    STEP(s + 5, 2, af1, af0, "vmcnt(4)", 1, 1);
  }
  STEP(30, 0, af0, af1, "vmcnt(4)", 1, 1);   // B(33), A(31)
  STEP(31, 1, af1, af0, "vmcnt(4)", 1, 1);   // B(34), A(32)
  STEP(32, 2, af0, af1, "vmcnt(4)", 1, 1);   // B(35), A(33)
  STEP(33, 0, af1, af0, "vmcnt(4)", 0, 1);   // A(34); drains B(34),A(33)
  STEP(34, 1, af0, af1, "vmcnt(0)", 0, 1);   // A(35); full drain (B35,A34)
  STEP(35, 2, af1, af0, "vmcnt(0)", 0, 0);   // drains A(35)

  // ---- epilogue: store s16/f32 + per-channel stats ----
  int Sl[8] = {0,0,0,0,0,0,0,0}, Ql[8] = {0,0,0,0,0,0,0,0};
#pragma unroll
  for (int i = 0; i < 4; ++i) {
    int R = Mbase + ar0 + i*16 + quad*4;   // rows R..R+3 (4-aligned, PIX%4==0)
    int nR = R / PIX, plR = R % PIX;
#pragma unroll
    for (int j = 0; j < 8; ++j) {
      int colo = bc0 + j*16 + lm;
      v4i a = acc[i][j];
      size_t idx = ((size_t)nR*CC + colo)*PIX + plR;
      if (S16) {
        int2 pk;
        pk.x = (a.x & 0xFFFF) | (a.y << 16);
        pk.y = (a.z & 0xFFFF) | (a.w << 16);
        *(int2*)(s16out + idx) = pk;
      } else {
        *(float4*)(f32out + idx) =
            make_float4((float)a.x, (float)a.y, (float)a.z, (float)a.w);
      }
      Sl[j] += a.x + a.y + a.z + a.w;
      Ql[j] += a.x*a.x + a.y*a.y + a.z*a.z + a.w*a.w;
    }
  }
#pragma unroll
  for (int j = 0; j < 8; ++j) {
    int S = Sl[j], Q = Ql[j];
    S += __shfl_xor(S, 16); S += __shfl_xor(S, 32);   // reduce over quads
    Q += __shfl_xor(Q, 16); Q += __shfl_xor(Q, 32);
    if (quad == 0) {
      atomicAdd(&colS[bc0 + j*16 + lm], S);
      atomicAdd(&colQ[bc0 + j*16 + lm], Q);
    }
  }
  __syncthreads();
  atomicAdd(&sumS[t], (u64)(long long)colS[t]);   // 2's-comp wrap ok
  atomicAdd(&sumSS[t], (u64)(long long)colQ[t]);
}

// ---------------------------------------------------------------------------
// Per-channel BN fold: out = clip(s*A + B)
// ---------------------------------------------------------------------------
__global__ void finalize_stats(
    const long long* __restrict__ sumS, const long long* __restrict__ sumSS,
    const float* __restrict__ swv,
    const float* __restrict__ gamma, const float* __restrict__ beta,
    float* __restrict__ AB) {
  int c = threadIdx.x;
  double mu  = (double)sumS[c]  / (double)M_TOT;
  double var = (double)sumSS[c] / (double)M_TOT - mu*mu;
  double sw  = (double)swv[c];
  double inv = 1.0 / sqrt(sw*sw*var + 1e-5);
  double scale = (double)gamma[c] * sw * inv;
  double shift = (double)beta[c] - scale * mu;
  AB[c]      = (float)scale;
  AB[CC + c] = (float)shift;
}

__global__ __launch_bounds__(256) void bn_apply_s16(
    const short* __restrict__ s, float* __restrict__ out,
    const float* __restrict__ AB, int n8) {
  int i = blockIdx.x*256 + threadIdx.x;
  if (i >= n8) return;
  union { int4 v; short sh[8]; } u;
  u.v = ((const int4*)s)[i];
  int c = ((i*8) / PIX) & (CC-1);   // PIX % 8 == 0 -> c uniform across the 8
  float a = AB[c], b = AB[CC + c];
  float4 o0, o1;
  o0.x = fminf(1.f, fmaxf(-1.f, (float)u.sh[0]*a + b));
  o0.y = fminf(1.f, fmaxf(-1.f, (float)u.sh[1]*a + b));
  o0.z = fminf(1.f, fmaxf(-1.f, (float)u.sh[2]*a + b));
  o0.w = fminf(1.f, fmaxf(-1.f, (float)u.sh[3]*a + b));
  o1.x = fminf(1.f, fmaxf(-1.f, (float)u.sh[4]*a + b));
  o1.y = fminf(1.f, fmaxf(-1.f, (float)u.sh[5]*a + b));
  o1.z = fminf(1.f, fmaxf(-1.f, (float)u.sh[6]*a + b));
  o1.w = fminf(1.f, fmaxf(-1.f, (float)u.sh[7]*a + b));
  ((float4*)out)[2*i]   = o0;
  ((float4*)out)[2*i+1] = o1;
}

__global__ __launch_bounds__(256) void bn_apply_f32(
    float* __restrict__ out, const float* __restrict__ AB, int n4) {
  int i = blockIdx.x*256 + threadIdx.x;
  if (i >= n4) return;
  float4 v = ((float4*)out)[i];
  int c = ((i*4) / PIX) & (CC-1);
  float a = AB[c], b = AB[CC + c];
  v.x = fminf(1.f, fmaxf(-1.f, v.x*a + b));
  v.y = fminf(1.f, fmaxf(-1.f, v.y*a + b));
  v.z = fminf(1.f, fmaxf(-1.f, v.z*a + b));
  v.w = fminf(1.f, fmaxf(-1.f, v.w*a + b));
  ((float4*)out)[i] = v;
}

extern "C" void kernel_launch(void* const* d_in, const int* in_sizes, int n_in,
                              void* d_out, int out_size, void* d_ws, size_t ws_size,
                              hipStream_t stream) {
  (void)in_sizes; (void)n_in; (void)out_size;
  const float* x     = (const float*)d_in[0];
  const float* wt    = (const float*)d_in[1];
  const float* gamma = (const float*)d_in[2];
  const float* beta  = (const float*)d_in[3];
  float* out = (float*)d_out;

  char* ws = (char*)d_ws;
  size_t off = 0;
  signed char* actq = (signed char*)(ws + off);
  off += ACTQ_BYTES;             off = (off + 255) & ~(size_t)255;
  signed char* wq = (signed char*)(ws + off);
  off += WQ_BYTES;               off = (off + 255) & ~(size_t)255;
  float* swv = (float*)(ws + off); off += 1024;
  float* AB  = (float*)(ws + off); off += 2048;
  long long* sumS  = (long long*)(ws + off); off += 2048;
  long long* sumSS = (long long*)(ws + off); off += 2048;
  off = (off + 255) & ~(size_t)255;
  short* sbuf = (short*)(ws + off);
  bool s16 = (ws_size >= off + SBUF_BYTES);

  pack_weights_i8<<<256, 256, 0, stream>>>(wt, wq, swv, sumS, sumSS);
  pack_acts_i8<<<dim3(53, NB), 256, 0, stream>>>(x, actq);  // borders zeroed here
  if (s16) {
    bconv_mfma<true><<<dim3(M_TOT/BM, 1), 256, 0, stream>>>(
        actq, wq, sbuf, nullptr, (u64*)sumS, (u64*)sumSS);
  } else {
    bconv_mfma<false><<<dim3(M_TOT/BM, 1), 256, 0, stream>>>(
        actq, wq, nullptr, out, (u64*)sumS, (u64*)sumSS);
  }
  finalize_stats<<<1, 256, 0, stream>>>(sumS, sumSS, swv, gamma, beta, AB);
  if (s16) {
    bn_apply_s16<<<(M_TOT*CC/8 + 255)/256, 256, 0, stream>>>(
        sbuf, out, AB, M_TOT*CC/8);
  } else {
    bn_apply_f32<<<(M_TOT*CC/4 + 255)/256, 256, 0, stream>>>(
        out, AB, M_TOT*CC/4);
  }
}

// Round 5
// 151.658 us; speedup vs baseline: 1.3994x; 1.3994x over previous
//
#include <hip/hip_runtime.h>
#include <math.h>

// Problem constants
#define HH 56
#define WW 56
#define NB 32
#define CC 256
#define PIX 3136               // 56*56
#define M_TOT 100352           // 32*3136
#define PADH 58
#define PADW 58
#define ACTQ_BYTES ((size_t)NB*PADH*PADW*CC)   // 27,553,792
#define WQ_BYTES ((size_t)9*CC*CC)             // 589,824
#define SBUF_BYTES ((size_t)M_TOT*CC*2)        // 51,380,224
#define BM 128
#define BN 256

typedef unsigned int u32;
typedef unsigned long long u64;
typedef int v4i __attribute__((ext_vector_type(4)));

// global_load_lds, width 16 (global -> LDS DMA; dest = wave base + lane*16)
typedef const __attribute__((address_space(1))) unsigned int* as1_u32p;
typedef __attribute__((address_space(3))) unsigned int* as3_u32p;
#define GLOAD_LDS16(g, l) \
  __builtin_amdgcn_global_load_lds((as1_u32p)(g), (as3_u32p)(l), 16, 0, 0)

// ---------------------------------------------------------------------------
// Pack weights: per-co mean (double), unbiased std, sw = 2^round(log2 mean|bw|),
// sign bytes wq[tap][co][ci] in {-1,+1}. Zeroes stat accumulators.
// ---------------------------------------------------------------------------
__global__ __launch_bounds__(256) void pack_weights_i8(
    const float* __restrict__ wt, signed char* __restrict__ wq,
    float* __restrict__ swv,
    long long* __restrict__ sumS, long long* __restrict__ sumSS) {
  int co = blockIdx.x;
  int t  = threadIdx.x;          // = ci
  int lane = t & 63, wid = t >> 6;

  float wv[9];
  const float* wp = wt + ((size_t)co*CC + t)*9;
  double psum = 0.0;
#pragma unroll
  for (int k = 0; k < 9; ++k) { wv[k] = wp[k]; psum += (double)wv[k]; }

  __shared__ double redm[4];
#pragma unroll
  for (int off = 32; off > 0; off >>= 1) psum += __shfl_xor(psum, off);
  if (lane == 0) redm[wid] = psum;
  __syncthreads();
  double mean = (redm[0]+redm[1]+redm[2]+redm[3]) * (1.0/2304.0);

  double pabs = 0.0, psq = 0.0;
#pragma unroll
  for (int k = 0; k < 9; ++k) {
    double d = (double)wv[k] - mean;
    pabs += fabs(d);
    psq  += d*d;
  }
#pragma unroll
  for (int off = 32; off > 0; off >>= 1) {
    pabs += __shfl_xor(pabs, off);
    psq  += __shfl_xor(psq,  off);
  }
  __shared__ double reda[4], redq[4];
  if (lane == 0) { reda[wid] = pabs; redq[wid] = psq; }
  __syncthreads();
  if (t == 0) {
    double sa = reda[0]+reda[1]+reda[2]+reda[3];
    double sq = redq[0]+redq[1]+redq[2]+redq[3];
    double stdv = sqrt(sq / 2303.0);                 // torch unbiased std
    double mabs = (sa * (1.0/2304.0)) / stdv;        // mean|bw|
    swv[co] = (float)exp2(rint(log2(mabs)));         // round half-to-even
    sumS[co]  = 0;
    sumSS[co] = 0;
  }
  // sign bytes: wq[k][co][ci]
#pragma unroll
  for (int k = 0; k < 9; ++k)
    wq[((size_t)k*CC + co)*CC + t] =
        (((double)wv[k] - mean) > 0.0) ? (signed char)1 : (signed char)-1;
}

// ---------------------------------------------------------------------------
// Pack activations: sign(x) -> i8 channel-last padded [n][ph][pw][ci].
// Border cells written as zeros here (memset fused away).
// ---------------------------------------------------------------------------
__global__ __launch_bounds__(256) void pack_acts_i8(
    const float* __restrict__ x, signed char* __restrict__ actq) {
  int n = blockIdx.y, tile = blockIdx.x;               // 53 tiles of 64 padded-pl
  int lane = threadIdx.x & 63, cw = threadIdx.x >> 6;  // cw: 64-ci group
  int pp = tile*64 + lane;
  if (pp >= PADH*PADW) return;
  int ph = pp / PADW, pw = pp - ph*PADW;
  signed char* dst = actq + ((size_t)(n*PADH + ph)*PADW + pw)*CC + cw*64;
  if (ph == 0 || ph == PADH-1 || pw == 0 || pw == PADW-1) {
    uint4 z = make_uint4(0u, 0u, 0u, 0u);
#pragma unroll
    for (int q = 0; q < 4; ++q) ((uint4*)dst)[q] = z;
    return;
  }
  int h = ph - 1, w = pw - 1;
  const float* xp = x + ((size_t)(n*CC + cw*64))*PIX + h*WW + w;
  u32 wrd[16];
#pragma unroll
  for (int c16 = 0; c16 < 16; ++c16) {
    u32 v = 0;
#pragma unroll
    for (int b = 0; b < 4; ++b) {
      float f = xp[(size_t)(c16*4 + b)*PIX];
      v |= (f > 0.0f ? 0x01u : 0xFFu) << (8*b);   // +1 / -1 as i8
    }
    wrd[c16] = v;
  }
#pragma unroll
  for (int q = 0; q < 4; ++q)
    ((uint4*)dst)[q] = make_uint4(wrd[4*q], wrd[4*q+1], wrd[4*q+2], wrd[4*q+3]);
}

// ---------------------------------------------------------------------------
// Binary implicit-GEMM conv, mfma_i32_16x16x64_i8. Block 128x256 (grid 784),
// 4 waves, wave tile 64x128 (32 MFMA/stage). Conv core = round-3 verified
// structure (92us): 3-deep LDS pipeline, counted vmcnt(12) (never 0 in main
// loop), 2 raw barriers/stage, XOR chunk-swizzle (0 bank conflicts), setprio
// around the MFMA cluster.
// Round 5: TILE-LOCAL sbuf LAYOUT. Old epilogue wrote int2 at PIX-strided
// columns in NCHW -> TCC partial-line amplification (WRITE 88MB vs 51MB
// logical). New: sbuf[tile][col 256][row 128] -> epilogue writes are dense
// within the tile (full sectors, zero amplification); bn_apply_s16 inverts
// the mapping (reads stay linear; out-writes become 512B runs per 16 lanes).
// ---------------------------------------------------------------------------

// stage SN (tap SN>>2, k-chunk SN&3) into buffer BUF (0/1/2)
// A: 8KB (128 rows x 64B), B: 16KB (256 cols x 64B); 6 gload_lds per thread.
#define STAGEM(SN, BUF) do {                                              \
    int tn_ = (SN) >> 2, kn_ = (SN) & 3;                                  \
    int aoff_ = ((tn_/3 - 1)*PADW + (tn_%3 - 1))*CC + kn_*64;             \
    int boff_ = tn_*65536 + kn_*64;                                       \
    char* nb_ = (char*)lds + (BUF)*24576;                                 \
    GLOAD_LDS16(pA0 + aoff_, nb_ + ldst);                                 \
    GLOAD_LDS16(pA1 + aoff_, nb_ + 4096 + ldst);                          \
    GLOAD_LDS16(pB0 + boff_, nb_ + 8192 + ldst);                          \
    GLOAD_LDS16(pB1 + boff_, nb_ + 12288 + ldst);                         \
    GLOAD_LDS16(pB2 + boff_, nb_ + 16384 + ldst);                         \
    GLOAD_LDS16(pB3 + boff_, nb_ + 20480 + ldst);                         \
  } while (0)

// one K-stage: wait stage S landed (counted), read frags, fence+barrier,
// prefetch stage S+3 into the freed buffer, 32 MFMAs under setprio(1).
#define STEPM(S, BUF, WTXT, DOSTAGE) do {                                 \
    asm volatile("s_waitcnt " WTXT ::: "memory");                         \
    __builtin_amdgcn_s_barrier();                                         \
    const char* cb_ = (const char*)lds + (BUF)*24576;                     \
    v4i af[4], bf[8];                                                     \
    _Pragma("unroll")                                                     \
    for (int i = 0; i < 4; ++i)                                           \
      af[i] = *(const v4i*)(cb_ + (ar0 + i*16 + lm)*64 + rdo);            \
    _Pragma("unroll")                                                     \
    for (int j = 0; j < 8; ++j)                                           \
      bf[j] = *(const v4i*)(cb_ + 8192 + (bc0 + j*16 + lm)*64 + rdo);     \
    asm volatile("s_waitcnt lgkmcnt(0)" ::: "memory");                    \
    __builtin_amdgcn_s_barrier();                                         \
    if (DOSTAGE) { STAGEM((S) + 3, BUF); }                                \
    __builtin_amdgcn_s_setprio(1);                                        \
    _Pragma("unroll")                                                     \
    for (int i = 0; i < 4; ++i)                                           \
      _Pragma("unroll")                                                   \
      for (int j = 0; j < 8; ++j)                                         \
        acc[i][j] = __builtin_amdgcn_mfma_i32_16x16x64_i8(af[i], bf[j],   \
                                                          acc[i][j], 0, 0, 0); \
    __builtin_amdgcn_s_setprio(0);                                        \
  } while (0)

template <bool S16>
__global__ __launch_bounds__(256, 2) void bconv_mfma(
    const signed char* __restrict__ actq, const signed char* __restrict__ wq,
    short* __restrict__ s16out, float* __restrict__ f32out,
    u64* __restrict__ sumS, u64* __restrict__ sumSS) {
  __shared__ char lds[73728] __attribute__((aligned(16)));  // 3 x (A 8K | B 16K)
  __shared__ int colS[256], colQ[256];

  int t = threadIdx.x;
  int lane = t & 63, wv = t >> 6;
  int lm = lane & 15, quad = lane >> 4;
  int ar0 = (wv & 1) * 64;         // wave A-row base in tile (2 row groups)
  int bc0 = (wv >> 1) * 128;       // wave B-col base in tile (2 col groups)
  int Mbase = blockIdx.x * BM;

  colS[t] = 0; colQ[t] = 0;

  // staging: thread t -> A rows r, r+64 / B cols r, r+64, r+128, r+192.
  // LDS dest is LINEAR slot (row, c16); global source chunk is XOR-swizzled
  // cs = c16 ^ ((r>>1)&3)  (row+64k keeps the same key).
  int r = t >> 2, c16 = t & 3;
  int cs = c16 ^ ((r >> 1) & 3);
  const signed char *pA0, *pA1;
  {
    int P = Mbase + r;
    int n_ = P / PIX, pl_ = P % PIX, h_ = pl_ / WW, w_ = pl_ % WW;
    pA0 = actq + ((size_t)(n_*PADH + h_+1)*PADW + (w_+1))*CC + cs*16;
    P += 64;
    n_ = P / PIX; pl_ = P % PIX; h_ = pl_ / WW; w_ = pl_ % WW;
    pA1 = actq + ((size_t)(n_*PADH + h_+1)*PADW + (w_+1))*CC + cs*16;
  }
  const signed char* pB0 = wq + (size_t)r*CC + cs*16;
  const signed char* pB1 = pB0 +  64*CC;
  const signed char* pB2 = pB0 + 128*CC;
  const signed char* pB3 = pB0 + 192*CC;
  int ldst = t*16;                 // LDS dest: [row][64B] contiguous in t

  // read side: lane (lm,quad) wants global chunk=quad of row ..+lm ->
  // LDS slot quad ^ ((row>>1)&3); (row>>1)&3 == (lm>>1)&3 for 16-aligned bases
  int rdo = (quad ^ ((lm >> 1) & 3)) * 16;

  v4i acc[4][8];
#pragma unroll
  for (int i = 0; i < 4; ++i)
#pragma unroll
    for (int j = 0; j < 8; ++j) acc[i][j] = 0;

  // prologue: fill the 3-deep pipeline (18 loads in flight)
  STAGEM(0, 0);
  STAGEM(1, 1);
  STAGEM(2, 2);

  // stage s: tap = s>>2 (0..8), kq = s&3 (64B k-chunk within tap); 36 stages.
  // steady state: wait vmcnt(12) -> stage s landed, 2 stages (12 loads)
  // stay in flight across the barriers.
#pragma unroll 1
  for (int s = 0; s < 33; s += 3) {
    STEPM(s,     0, "vmcnt(12)", true);
    STEPM(s + 1, 1, "vmcnt(12)", true);
    STEPM(s + 2, 2, "vmcnt(12)", true);
  }
  STEPM(33, 0, "vmcnt(12)", false);  // S34,S35 in flight (12) -> drains S33
  STEPM(34, 1, "vmcnt(6)",  false);  // S35 in flight (6) -> drains S34
  STEPM(35, 2, "vmcnt(0)",  false);  // drain

  // ---- epilogue: store s16 (tile-local layout) / f32 + per-channel stats ----
  int Sl[8] = {0,0,0,0,0,0,0,0}, Ql[8] = {0,0,0,0,0,0,0,0};
  if (S16) {
    // sbuf layout: [tile][col 0..255][row 0..127] shorts; dense tile writes.
    short* tb = s16out + (size_t)blockIdx.x * (BM*BN);
#pragma unroll
    for (int i = 0; i < 4; ++i) {
      int rhat = ar0 + i*16 + quad*4;    // rows rhat..rhat+3 (4-aligned)
#pragma unroll
      for (int j = 0; j < 8; ++j) {
        int colo = bc0 + j*16 + lm;
        v4i a = acc[i][j];
        int2 pk;
        pk.x = (a.x & 0xFFFF) | (a.y << 16);
        pk.y = (a.z & 0xFFFF) | (a.w << 16);
        *(int2*)(tb + (size_t)colo*BM + rhat) = pk;
        Sl[j] += a.x + a.y + a.z + a.w;
        Ql[j] += a.x*a.x + a.y*a.y + a.z*a.z + a.w*a.w;
      }
    }
  } else {
#pragma unroll
    for (int i = 0; i < 4; ++i) {
      int R = Mbase + ar0 + i*16 + quad*4;   // rows R..R+3 (PIX%4==0)
      int nR = R / PIX, plR = R % PIX;
#pragma unroll
      for (int j = 0; j < 8; ++j) {
        int colo = bc0 + j*16 + lm;
        v4i a = acc[i][j];
        size_t idx = ((size_t)nR*CC + colo)*PIX + plR;
        *(float4*)(f32out + idx) =
            make_float4((float)a.x, (float)a.y, (float)a.z, (float)a.w);
        Sl[j] += a.x + a.y + a.z + a.w;
        Ql[j] += a.x*a.x + a.y*a.y + a.z*a.z + a.w*a.w;
      }
    }
  }
#pragma unroll
  for (int j = 0; j < 8; ++j) {
    int S = Sl[j], Q = Ql[j];
    S += __shfl_xor(S, 16); S += __shfl_xor(S, 32);   // reduce over quads
    Q += __shfl_xor(Q, 16); Q += __shfl_xor(Q, 32);
    if (quad == 0) {
      atomicAdd(&colS[bc0 + j*16 + lm], S);
      atomicAdd(&colQ[bc0 + j*16 + lm], Q);
    }
  }
  __syncthreads();
  atomicAdd(&sumS[t], (u64)(long long)colS[t]);   // 2's-comp wrap ok
  atomicAdd(&sumSS[t], (u64)(long long)colQ[t]);
}

// ---------------------------------------------------------------------------
// Per-channel BN fold: out = clip(s*A + B)
// ---------------------------------------------------------------------------
__global__ void finalize_stats(
    const long long* __restrict__ sumS, const long long* __restrict__ sumSS,
    const float* __restrict__ swv,
    const float* __restrict__ gamma, const float* __restrict__ beta,
    float* __restrict__ AB) {
  int c = threadIdx.x;
  double mu  = (double)sumS[c]  / (double)M_TOT;
  double var = (double)sumSS[c] / (double)M_TOT - mu*mu;
  double sw  = (double)swv[c];
  double inv = 1.0 / sqrt(sw*sw*var + 1e-5);
  double scale = (double)gamma[c] * sw * inv;
  double shift = (double)beta[c] - scale * mu;
  AB[c]      = (float)scale;
  AB[CC + c] = (float)shift;
}

// Reads sbuf in tile-local layout [tile][col 256][row 128]; writes NCHW f32.
// Thread i handles 8 consecutive rows of one (tile,col): linear 16B read;
// out writes 32B contiguous per thread, 512B runs per 16 consecutive threads.
__global__ __launch_bounds__(256) void bn_apply_s16(
    const short* __restrict__ s, float* __restrict__ out,
    const float* __restrict__ AB, int n8) {
  int i = blockIdx.x*256 + threadIdx.x;
  if (i >= n8) return;
  union { int4 v; short sh[8]; } u;
  u.v = ((const int4*)s)[i];
  int base   = i*8;
  int tile   = base >> 15;          // BM*BN = 32768 shorts per tile
  int within = base & 32767;
  int col    = within >> 7;         // 0..255  (channel)
  int rh     = within & 127;        // row in tile, multiple of 8
  int R  = tile*BM + rh;            // global M index; 8-row group never
  int n_ = R / PIX, pl = R % PIX;   // straddles n (PIX%8==0, BM%8==0)
  float a = AB[col], b = AB[CC + col];
  float* op = out + ((size_t)n_*CC + col)*PIX + pl;
  float4 o0, o1;
  o0.x = fminf(1.f, fmaxf(-1.f, (float)u.sh[0]*a + b));
  o0.y = fminf(1.f, fmaxf(-1.f, (float)u.sh[1]*a + b));
  o0.z = fminf(1.f, fmaxf(-1.f, (float)u.sh[2]*a + b));
  o0.w = fminf(1.f, fmaxf(-1.f, (float)u.sh[3]*a + b));
  o1.x = fminf(1.f, fmaxf(-1.f, (float)u.sh[4]*a + b));
  o1.y = fminf(1.f, fmaxf(-1.f, (float)u.sh[5]*a + b));
  o1.z = fminf(1.f, fmaxf(-1.f, (float)u.sh[6]*a + b));
  o1.w = fminf(1.f, fmaxf(-1.f, (float)u.sh[7]*a + b));
  ((float4*)op)[0] = o0;
  ((float4*)op)[1] = o1;
}

__global__ __launch_bounds__(256) void bn_apply_f32(
    float* __restrict__ out, const float* __restrict__ AB, int n4) {
  int i = blockIdx.x*256 + threadIdx.x;
  if (i >= n4) return;
  float4 v = ((float4*)out)[i];
  int c = ((i*4) / PIX) & (CC-1);
  float a = AB[c], b = AB[CC + c];
  v.x = fminf(1.f, fmaxf(-1.f, v.x*a + b));
  v.y = fminf(1.f, fmaxf(-1.f, v.y*a + b));
  v.z = fminf(1.f, fmaxf(-1.f, v.z*a + b));
  v.w = fminf(1.f, fmaxf(-1.f, v.w*a + b));
  ((float4*)out)[i] = v;
}

extern "C" void kernel_launch(void* const* d_in, const int* in_sizes, int n_in,
                              void* d_out, int out_size, void* d_ws, size_t ws_size,
                              hipStream_t stream) {
  (void)in_sizes; (void)n_in; (void)out_size;
  const float* x     = (const float*)d_in[0];
  const float* wt    = (const float*)d_in[1];
  const float* gamma = (const float*)d_in[2];
  const float* beta  = (const float*)d_in[3];
  float* out = (float*)d_out;

  char* ws = (char*)d_ws;
  size_t off = 0;
  signed char* actq = (signed char*)(ws + off);
  off += ACTQ_BYTES;             off = (off + 255) & ~(size_t)255;
  signed char* wq = (signed char*)(ws + off);
  off += WQ_BYTES;               off = (off + 255) & ~(size_t)255;
  float* swv = (float*)(ws + off); off += 1024;
  float* AB  = (float*)(ws + off); off += 2048;
  long long* sumS  = (long long*)(ws + off); off += 2048;
  long long* sumSS = (long long*)(ws + off); off += 2048;
  off = (off + 255) & ~(size_t)255;
  short* sbuf = (short*)(ws + off);
  bool s16 = (ws_size >= off + SBUF_BYTES);

  pack_weights_i8<<<256, 256, 0, stream>>>(wt, wq, swv, sumS, sumSS);
  pack_acts_i8<<<dim3(53, NB), 256, 0, stream>>>(x, actq);  // borders zeroed here
  if (s16) {
    bconv_mfma<true><<<dim3(M_TOT/BM, 1), 256, 0, stream>>>(
        actq, wq, sbuf, nullptr, (u64*)sumS, (u64*)sumSS);
  } else {
    bconv_mfma<false><<<dim3(M_TOT/BM, 1), 256, 0, stream>>>(
        actq, wq, nullptr, out, (u64*)sumS, (u64*)sumSS);
  }
  finalize_stats<<<1, 256, 0, stream>>>(sumS, sumSS, swv, gamma, beta, AB);
  if (s16) {
    bn_apply_s16<<<(M_TOT*CC/8 + 255)/256, 256, 0, stream>>>(
        sbuf, out, AB, M_TOT*CC/8);
  } else {
    bn_apply_f32<<<(M_TOT*CC/4 + 255)/256, 256, 0, stream>>>(
        out, AB, M_TOT*CC/4);
  }
}